// Round 9
// baseline (9741.429 us; speedup 1.0000x reference)
//
#include <hip/hip_runtime.h>
#include <hip/hip_bf16.h>

// GRU: L=2, B=32, T=1024, H=512, OUT=512
// Round 9: R7 protocol (in-band LSB tags, full-burst retry — PASSED) plus:
//   - producers publish h as 32x 16B tagged granules (LDS transpose, aligned)
//     instead of 1024x 2B scattered stores (R7's suspected bottleneck)
//   - s_sleep(1) between failed retry bursts (LLC pressure relief)
// A (WG 0..15): layer-0 spine, W_hh0 in regs. B (WG 16..31): layer-1,
// W_hh1 in regs + W_ih1 in LDS. T-deep write-once buffers; k0 re-zeroes tags.

typedef _Float16 f16x8 __attribute__((ext_vector_type(8)));
typedef float f32x4 __attribute__((ext_vector_type(4)));
typedef unsigned short u16;
typedef unsigned int u32;
typedef u32 u32x2 __attribute__((ext_vector_type(2)));
typedef u32 u32x4 __attribute__((ext_vector_type(4)));

#define MFMA16(a,b,c) __builtin_amdgcn_mfma_f32_16x16x32_f16((a),(b),(c),0,0,0)
#define SB0 __builtin_amdgcn_sched_barrier(0)
#define VMC0 asm volatile("s_waitcnt vmcnt(0)" ::: "memory")
#define LGK0 asm volatile("s_waitcnt lgkmcnt(0)" ::: "memory")

static constexpr int B = 32, T = 1024, H = 512, G3 = 1536;
static constexpr u32 M = 0x00010001u;

// ws layout (bytes)
static constexpr size_t OFF_GX  = 0;                               // 96MB f16 [t][g*512+u][b]
static constexpr size_t OFF_H0  = OFF_GX + (size_t)T*G3*B*2;       // 32MB f16|LSB [t][b][u]
static constexpr size_t OFF_H1  = OFF_H0 + (size_t)T*B*H*2;        // 32MB f16|LSB [t][b][u]
static constexpr size_t OFF_W0  = OFF_H1 + (size_t)T*B*H*2;        // 1.5MB f16
static constexpr size_t OFF_H0I = OFF_W0 + (size_t)G3*H*2;         // 32KB f16
static constexpr size_t OFF_H1I = OFF_H0I + (size_t)B*H*2;         // 32KB f16
static constexpr size_t OFF_H1F = OFF_H1I + (size_t)B*H*2;         // 64KB f32
static constexpr size_t ZERO_BYTES = OFF_W0 - OFF_H0;              // 64MB

__device__ __forceinline__ u16 f2h(float x){ _Float16 h=(_Float16)x; return __builtin_bit_cast(u16,h); }
__device__ __forceinline__ float h2f(u16 u){ _Float16 h=__builtin_bit_cast(_Float16,u); return (float)h; }

// ---- device-scope (LLC) primitives ----
__device__ __forceinline__ f16x8 llc_ld16(const u16* p){   // no wait
  f16x8 r; asm volatile("global_load_dwordx4 %0, %1, off sc0 sc1" : "=v"(r) : "v"(p)); return r;
}
__device__ __forceinline__ f16x8 pl_ld16(const u16* p){    // plain, no wait
  f16x8 r; asm volatile("global_load_dwordx4 %0, %1, off" : "=v"(r) : "v"(p)); return r;
}
__device__ __forceinline__ void llc_st128(u16* p, u32x4 v){
  asm volatile("global_store_dwordx4 %0, %1, off sc0 sc1" :: "v"(p), "v"(v) : "memory");
}

__device__ __forceinline__ float fsig(float x){ return 1.f/(1.f+__expf(-x)); }
__device__ __forceinline__ float ftanh(float x){
  x = fminf(15.f, fmaxf(-15.f, x));
  float e = __expf(-2.f*x);
  return (1.f-e)/(1.f+e);
}
__device__ __forceinline__ float gxval(u32x2 g, int j){
  u32 w = (j & 2) ? g[1] : g[0];
  return h2f((u16)(w >> ((j & 1) * 16)));
}
__device__ __forceinline__ u32 lsb_acc(f16x8 v){
  u32x4 w = __builtin_bit_cast(u32x4, v);
  return w[0] & w[1] & w[2] & w[3];
}

// W fragments (f32 -> f16) into registers; rows gate*512+cu, cols kk*32+lk*8
__device__ __forceinline__ void load_wf(f16x8 (*wf)[16], const float* Wbase, int cu, int lk){
#pragma unroll
  for (int g=0; g<3; g++)
#pragma unroll
    for (int kk=0; kk<16; kk++){
      const float* s = Wbase + ((size_t)(g*512 + cu))*H + kk*32 + lk*8;
      f32x4 s0 = *(const f32x4*)s, s1 = *(const f32x4*)(s+4);
      f16x8 v;
#pragma unroll
      for (int e=0; e<4; e++){ v[e]=(_Float16)s0[e]; v[4+e]=(_Float16)s1[e]; }
      wf[g][kk] = v;
    }
}
// MFMA B-operand fragment from XOR-swizzled LDS weights [96 rows][512] f16
__device__ __forceinline__ f16x8 lds_frag(const u16* wlds, int lrbase, int l15, int lk, int kk){
  int lr = lrbase + l15;
  int byte = lr*1024 + (((((kk<<5)+(lk<<3))<<1)) ^ ((lr&7)<<4));
  return *(const f16x8*)((const char*)wlds + byte);
}

// fuse -> intra-wave LDS transpose -> 32x 16B tagged granule stores
__device__ __forceinline__ void store_tile(u16* tile, u16* dst_rowbase, int ubase,
                                           const float* hown, int lk, int l15, int lane){
#pragma unroll
  for (int j=0;j<4;j++) tile[(lk*4+j)*16 + l15] = f2h(hown[j]);
  LGK0; SB0;
  if (lane < 32){
    int r = lane >> 1, hf = lane & 1;
    f16x8 v = *(const f16x8*)(tile + r*16 + hf*8);   // 16B-aligned (tile aligned 16)
    u32x4 g = __builtin_bit_cast(u32x4, v);
    g[0] |= M; g[1] |= M; g[2] |= M; g[3] |= M;
    llc_st128(dst_rowbase + (size_t)r*H + ubase + hf*8, g);
  }
}

// ---------------- k0: prep ----------------
__global__ __launch_bounds__(256) void k0_prep(const float* __restrict__ wih,
                                               const float* __restrict__ h0in,
                                               u16* __restrict__ wih0f16,
                                               u16* __restrict__ h0i,
                                               u16* __restrict__ h1i,
                                               u32x4* __restrict__ zbase){
  int i = blockIdx.x*256 + threadIdx.x;                  // 65536 threads
  const int NZ = (int)(ZERO_BYTES / 16);
  u32x4 z; z[0]=0; z[1]=0; z[2]=0; z[3]=0;
  for (int idx=i; idx<NZ; idx+=65536) zbase[idx] = z;
  for (int idx=i; idx<G3*H; idx+=65536) wih0f16[idx] = f2h(wih[idx]);
  if (i < B*H){ h0i[i] = f2h(h0in[i]); h1i[i] = f2h(h0in[B*H + i]); }
}

// ---------------- k1: gx0 GEMM  (out [t][gate][u][b] f16) ----------------
__global__ __launch_bounds__(256) void k1_gx(const float* __restrict__ x,
                                             const u16* __restrict__ wih0,
                                             const float* __restrict__ bih0,
                                             u16* __restrict__ gxT){
  int t  = blockIdx.x / 6, nb = blockIdx.x % 6;
  int wave = threadIdx.x >> 6, lane = threadIdx.x & 63;
  int l15 = lane & 15, lk = lane >> 4;
  int colbase = nb*256 + wave*64;
  f32x4 acc[2][4] = {};
#pragma unroll 4
  for (int kk=0; kk<16; kk++){
    int k0 = kk*32 + lk*8;
    f16x8 a[2];
#pragma unroll
    for (int bm=0; bm<2; bm++){
      const f32x4* xp_ = (const f32x4*)(x + ((size_t)(bm*16+l15)*T + t)*H + k0);
      f32x4 x0 = xp_[0], x1 = xp_[1];
      f16x8 v;
#pragma unroll
      for (int q=0;q<4;q++){ v[q]=(_Float16)x0[q]; v[4+q]=(_Float16)x1[q]; }
      a[bm] = v;
    }
#pragma unroll
    for (int nt=0; nt<4; nt++){
      int col = colbase + nt*16 + l15;
      f16x8 bf = *(const f16x8*)(wih0 + (size_t)col*H + k0);
      acc[0][nt] = MFMA16(a[0], bf, acc[0][nt]);
      acc[1][nt] = MFMA16(a[1], bf, acc[1][nt]);
    }
  }
#pragma unroll
  for (int nt=0; nt<4; nt++){
    int col = colbase + nt*16 + l15;
    float bias = bih0[col];
#pragma unroll
    for (int bm=0; bm<2; bm++){
      u32 lo = (u32)f2h(acc[bm][nt][0]+bias) | ((u32)f2h(acc[bm][nt][1]+bias) << 16);
      u32 hi = (u32)f2h(acc[bm][nt][2]+bias) | ((u32)f2h(acc[bm][nt][3]+bias) << 16);
      u32x2 v; v[0]=lo; v[1]=hi;
      *(u32x2*)(gxT + ((size_t)t*G3 + col)*B + bm*16 + lk*4) = v;
    }
  }
}

// ---------------- k2: persistent recurrence (32 WGs) ----------------
__global__ __launch_bounds__(256,1) void k2_recur(const float* __restrict__ h0in,
    const float* __restrict__ Wih, const float* __restrict__ bih,
    const float* __restrict__ Whh, const float* __restrict__ bhh,
    const u16* __restrict__ gxT,
    u16* __restrict__ h0all, u16* __restrict__ h1all,
    const u16* __restrict__ h0i, const u16* __restrict__ h1i,
    float* __restrict__ h1fin)
{
  __shared__ __align__(16) u16 wlds[96*512];
  __shared__ __align__(16) u16 wtile[4*256];
  const int wg = blockIdx.x, tid = threadIdx.x;
  const int wave = tid >> 6, lane = tid & 63;
  const int l15 = lane & 15, lk = lane >> 4;
  const int bm = wave >> 1, ug = wave & 1;
  u16* tile = wtile + wave*256;

  if (wg < 16){
    // ================= A: layer-0 spine =================
    const int slot = wg;
    const int cu    = slot*32 + ug*16 + l15;
    const int ubase = slot*32 + ug*16;
    f16x8 wf[3][16]; load_wf(wf, Whh, cu, lk);
    const float bhr = bhh[cu], bhu = bhh[512+cu], bhn = bhh[1024+cu];
    float hown[4];
#pragma unroll
    for (int j=0;j<4;j++) hown[j] = h0in[(size_t)(bm*16+lk*4+j)*H + cu];

    u32x2 g0, g1, g2;
    { const u16* gp = gxT + ((size_t)0*G3 + cu)*B + bm*16 + lk*4;
      g0 = *(const u32x2*)gp; g1 = *(const u32x2*)(gp + (size_t)512*B);
      g2 = *(const u32x2*)(gp + (size_t)1024*B); }

    for (int t=0; t<T; t++){
      f16x8 af[16];
      if (t == 0){
        const u16* hr = h0i + (size_t)(bm*16+l15)*H + lk*8;
#pragma unroll
        for (int kk=0; kk<16; kk++) af[kk] = pl_ld16(hr + kk*32);
        VMC0; SB0;
      } else {
        const u16* hr = h0all + ((size_t)(t-1)*B + bm*16 + l15)*H + lk*8;
        for (;;){
#pragma unroll
          for (int kk=0; kk<16; kk++) af[kk] = llc_ld16(hr + kk*32);
          VMC0; SB0;
          u32 acc = M;
#pragma unroll
          for (int kk=0; kk<16; kk++) acc &= lsb_acc(af[kk]);
          if (__all((acc & M) == M)) break;
          __builtin_amdgcn_s_sleep(1);
        }
      }
      f32x4 aR{}, aU{}, aN{};
#pragma unroll
      for (int kk=0; kk<16; kk++){
        aR = MFMA16(af[kk], wf[0][kk], aR);
        aU = MFMA16(af[kk], wf[1][kk], aU);
        aN = MFMA16(af[kk], wf[2][kk], aN);
      }
#pragma unroll
      for (int j=0;j<4;j++){
        float r = fsig(gxval(g0,j) + aR[j] + bhr);
        float u = fsig(gxval(g1,j) + aU[j] + bhu);
        float n = ftanh(gxval(g2,j) + r*(aN[j] + bhn));
        hown[j] = u*hown[j] + (1.f-u)*n;
      }
      store_tile(tile, h0all + ((size_t)t*B + bm*16)*H, ubase, hown, lk, l15, lane);
      if (t+1 < T){                                       // gx prefetch (plain)
        const u16* gp = gxT + ((size_t)(t+1)*G3 + cu)*B + bm*16 + lk*4;
        g0 = *(const u32x2*)gp; g1 = *(const u32x2*)(gp + (size_t)512*B);
        g2 = *(const u32x2*)(gp + (size_t)1024*B);
      }
    }
  } else {
    // ================= B: layer-1 (h-side regs + x-side LDS) =================
    const int slot = wg - 16;
    for (int idx = tid; idx < 96*64; idx += 256){
      int lr = idx >> 6, k8 = idx & 63;
      int g = lr >> 5, uu = lr & 31;
      const float* src = Wih + (size_t)G3*H + ((size_t)(g*512 + slot*32 + uu))*H + k8*8;
      f32x4 s0=*(const f32x4*)src, s1=*(const f32x4*)(src+4);
      f16x8 v;
#pragma unroll
      for (int e=0;e<4;e++){ v[e]=(_Float16)s0[e]; v[4+e]=(_Float16)s1[e]; }
      *(f16x8*)((char*)wlds + lr*1024 + ((k8*16) ^ ((lr&7)<<4))) = v;
    }
    __syncthreads();

    const int cu    = slot*32 + ug*16 + l15;
    const int ubase = slot*32 + ug*16;
    f16x8 wfh[3][16]; load_wf(wfh, Whh + (size_t)G3*H, cu, lk);
    const float br  = bih[G3 + cu]       + bhh[G3 + cu];
    const float bu_ = bih[G3 + 512 + cu] + bhh[G3 + 512 + cu];
    const float bni = bih[G3 + 1024 + cu];
    const float bnh = bhh[G3 + 1024 + cu];
    float hown[4];
#pragma unroll
    for (int j=0;j<4;j++) hown[j] = h0in[(size_t)B*H + (size_t)(bm*16+lk*4+j)*H + cu];

    const size_t rowoff = (size_t)(bm*16 + l15)*H + lk*8;

    for (int t=0; t<T; t++){
      f16x8 ah[16], ax[16];
      const u16* xr = h0all + (size_t)t*(B*H) + rowoff;
      const u16* hr = (t==0) ? (h1i + rowoff)
                             : (h1all + (size_t)(t-1)*(B*H) + rowoff);
      for (;;){
        if (t == 0){
#pragma unroll
          for (int kk=0; kk<16; kk++) ah[kk] = pl_ld16(hr + kk*32);
        } else {
#pragma unroll
          for (int kk=0; kk<16; kk++) ah[kk] = llc_ld16(hr + kk*32);
        }
#pragma unroll
        for (int kk=0; kk<16; kk++) ax[kk] = llc_ld16(xr + kk*32);
        VMC0; SB0;
        u32 acc = M;
#pragma unroll
        for (int kk=0; kk<16; kk++) acc &= lsb_acc(ax[kk]);
        if (t > 0){
#pragma unroll
          for (int kk=0; kk<16; kk++) acc &= lsb_acc(ah[kk]);
        }
        if (__all((acc & M) == M)) break;
        __builtin_amdgcn_s_sleep(1);
      }
      SB0;
      f32x4 hR{}, hU{}, hN{};
#pragma unroll
      for (int kk=0; kk<16; kk++){
        hR = MFMA16(ah[kk], wfh[0][kk], hR);
        hU = MFMA16(ah[kk], wfh[1][kk], hU);
        hN = MFMA16(ah[kk], wfh[2][kk], hN);
      }
      f32x4 xR{}, xU{}, xN{};
#pragma unroll
      for (int kk=0; kk<16; kk++){
        xR = MFMA16(ax[kk], lds_frag(wlds,      ug*16, l15, lk, kk), xR);
        xU = MFMA16(ax[kk], lds_frag(wlds, 32 + ug*16, l15, lk, kk), xU);
        xN = MFMA16(ax[kk], lds_frag(wlds, 64 + ug*16, l15, lk, kk), xN);
      }
#pragma unroll
      for (int j=0;j<4;j++){
        float r = fsig(xR[j] + hR[j] + br);
        float u = fsig(xU[j] + hU[j] + bu_);
        float n = ftanh(xN[j] + bni + r*(hN[j] + bnh));
        hown[j] = u*hown[j] + (1.f-u)*n;
        if (t == T-1) h1fin[(size_t)(bm*16+lk*4+j)*H + cu] = hown[j];
      }
      store_tile(tile, h1all + ((size_t)t*B + bm*16)*H, ubase, hown, lk, l15, lane);
    }
  }
}

// ---------------- k3: FC ----------------
__global__ __launch_bounds__(256) void k3_fc(const float* __restrict__ h1fin,
                                             const float* __restrict__ fcW,
                                             const float* __restrict__ fcb,
                                             float* __restrict__ out){
  int g = blockIdx.x*256 + threadIdx.x;     // 16384
  int b = g >> 9, o = g & 511;
  const f32x4* w = (const f32x4*)(fcW + (size_t)o*H);
  const f32x4* h = (const f32x4*)(h1fin + (size_t)b*H);
  float acc = fcb[o];
#pragma unroll 4
  for (int k=0;k<128;k++){
    f32x4 wv = w[k], hv = h[k];
    acc += wv[0]*hv[0] + wv[1]*hv[1] + wv[2]*hv[2] + wv[3]*hv[3];
  }
  out[g] = acc;
}

extern "C" void kernel_launch(void* const* d_in, const int* in_sizes, int n_in,
                              void* d_out, int out_size, void* d_ws, size_t ws_size,
                              hipStream_t stream) {
  const float* x    = (const float*)d_in[0];
  const float* h0   = (const float*)d_in[1];
  const float* Wih  = (const float*)d_in[2];
  const float* bihv = (const float*)d_in[3];
  const float* Whh  = (const float*)d_in[4];
  const float* bhhv = (const float*)d_in[5];
  const float* fcW  = (const float*)d_in[6];
  const float* fcb  = (const float*)d_in[7];
  float* out = (float*)d_out;

  char* ws = (char*)d_ws;
  u16* gxT     = (u16*)(ws + OFF_GX);
  u16* h0all   = (u16*)(ws + OFF_H0);
  u16* h1all   = (u16*)(ws + OFF_H1);
  u16* wih0f16 = (u16*)(ws + OFF_W0);
  u16* h0i     = (u16*)(ws + OFF_H0I);
  u16* h1i     = (u16*)(ws + OFF_H1I);
  float* h1fin = (float*)(ws + OFF_H1F);

  k0_prep<<<256, 256, 0, stream>>>(Wih, h0, wih0f16, h0i, h1i, (u32x4*)(ws + OFF_H0));
  k1_gx<<<T*6, 256, 0, stream>>>(x, wih0f16, bihv, gxT);
  k2_recur<<<32, 256, 0, stream>>>(h0, Wih, bihv, Whh, bhhv, gxT,
                                   h0all, h1all, h0i, h1i, h1fin);
  k3_fc<<<64, 256, 0, stream>>>(h1fin, fcW, fcb, out);
}

// Round 10
// 7982.182 us; speedup vs baseline: 1.2204x; 1.2204x over previous
//
#include <hip/hip_runtime.h>
#include <hip/hip_bf16.h>

// GRU: L=2, B=32, T=1024, H=512, OUT=512
// Round 10: R2's canary protocol (best measured) minus its serial fat:
//   - B: ONE dual poll (canA(t) + canB(t-1), single issue) + ONE combined
//     32-load h0/h1 burst + both MFMA blocks  (was ~4 serial RTs, now ~2)
//   - producers: LDS-transpose -> one 16B granule store per lane (fast drain)
//   - per-WG canary (16 words = one cache line to poll), VMC0+syncthreads first
//   - W_hh0/W_hh1 in registers; W_ih1 in LDS (swizzled); gx prefetch depth-1
// A (WG 0..15): layer-0 spine. B (WG 16..31): layer-1. T-deep h buffers.

typedef _Float16 f16x8 __attribute__((ext_vector_type(8)));
typedef float f32x4 __attribute__((ext_vector_type(4)));
typedef unsigned short u16;
typedef unsigned int u32;
typedef u32 u32x2 __attribute__((ext_vector_type(2)));
typedef u32 u32x4 __attribute__((ext_vector_type(4)));

#define MFMA16(a,b,c) __builtin_amdgcn_mfma_f32_16x16x32_f16((a),(b),(c),0,0,0)
#define SB0 __builtin_amdgcn_sched_barrier(0)
#define VMC0 asm volatile("s_waitcnt vmcnt(0)" ::: "memory")
#define LGK0 asm volatile("s_waitcnt lgkmcnt(0)" ::: "memory")

static constexpr int B = 32, T = 1024, H = 512, G3 = 1536;

// ws layout (bytes)
static constexpr size_t OFF_GX  = 0;                               // 96MB f16 [t][g*512+u][b]
static constexpr size_t OFF_H0  = OFF_GX + (size_t)T*G3*B*2;       // 32MB f16 [t][b][u]
static constexpr size_t OFF_H1  = OFF_H0 + (size_t)T*B*H*2;        // 32MB f16 [t][b][u]
static constexpr size_t OFF_CA  = OFF_H1 + (size_t)T*B*H*2;        // 64KB u32 [T][16]
static constexpr size_t OFF_CB  = OFF_CA + (size_t)T*16*4;         // 64KB u32 [T][16]
static constexpr size_t OFF_W0  = OFF_CB + (size_t)T*16*4;         // 1.5MB f16
static constexpr size_t OFF_H0I = OFF_W0 + (size_t)G3*H*2;         // 32KB f16
static constexpr size_t OFF_H1I = OFF_H0I + (size_t)B*H*2;         // 32KB f16
static constexpr size_t OFF_H1F = OFF_H1I + (size_t)B*H*2;         // 64KB f32

__device__ __forceinline__ u16 f2h(float x){ _Float16 h=(_Float16)x; return __builtin_bit_cast(u16,h); }
__device__ __forceinline__ float h2f(u16 u){ _Float16 h=__builtin_bit_cast(_Float16,u); return (float)h; }

// ---- device-scope (LLC) primitives ----
__device__ __forceinline__ u32 llc_poll(const u32* p){
  u32 r; asm volatile("global_load_dword %0, %1, off sc0 sc1\n\ts_waitcnt vmcnt(0)"
                      : "=v"(r) : "v"(p) : "memory"); return r;
}
__device__ __forceinline__ void llc_poll2(const u32* p, const u32* q, u32& a, u32& b){
  asm volatile("global_load_dword %0, %2, off sc0 sc1\n\t"
               "global_load_dword %1, %3, off sc0 sc1\n\t"
               "s_waitcnt vmcnt(0)"
               : "=&v"(a), "=&v"(b) : "v"(p), "v"(q) : "memory");
}
__device__ __forceinline__ f16x8 llc_ld16(const u16* p){   // no wait
  f16x8 r; asm volatile("global_load_dwordx4 %0, %1, off sc0 sc1" : "=v"(r) : "v"(p)); return r;
}
__device__ __forceinline__ f16x8 pl_ld16(const u16* p){    // plain, no wait
  f16x8 r; asm volatile("global_load_dwordx4 %0, %1, off" : "=v"(r) : "v"(p)); return r;
}
__device__ __forceinline__ void llc_st128(u16* p, u32x4 v){
  asm volatile("global_store_dwordx4 %0, %1, off sc0 sc1" :: "v"(p), "v"(v) : "memory");
}
__device__ __forceinline__ void llc_st32(u32* p, u32 v){
  asm volatile("global_store_dword %0, %1, off sc0 sc1" :: "v"(p), "v"(v) : "memory");
}

__device__ __forceinline__ float fsig(float x){ return 1.f/(1.f+__expf(-x)); }
__device__ __forceinline__ float ftanh(float x){
  x = fminf(15.f, fmaxf(-15.f, x));
  float e = __expf(-2.f*x);
  return (1.f-e)/(1.f+e);
}
__device__ __forceinline__ float gxval(u32x2 g, int j){
  u32 w = (j & 2) ? g[1] : g[0];
  return h2f((u16)(w >> ((j & 1) * 16)));
}

// W fragments (f32 -> f16) into registers; rows gate*512+cu, cols kk*32+lk*8
__device__ __forceinline__ void load_wf(f16x8 (*wf)[16], const float* Wbase, int cu, int lk){
#pragma unroll
  for (int g=0; g<3; g++)
#pragma unroll
    for (int kk=0; kk<16; kk++){
      const float* s = Wbase + ((size_t)(g*512 + cu))*H + kk*32 + lk*8;
      f32x4 s0 = *(const f32x4*)s, s1 = *(const f32x4*)(s+4);
      f16x8 v;
#pragma unroll
      for (int e=0; e<4; e++){ v[e]=(_Float16)s0[e]; v[4+e]=(_Float16)s1[e]; }
      wf[g][kk] = v;
    }
}
// MFMA B-operand fragment from XOR-swizzled LDS weights [96 rows][512] f16
__device__ __forceinline__ f16x8 lds_frag(const u16* wlds, int lrbase, int l15, int lk, int kk){
  int lr = lrbase + l15;
  int byte = lr*1024 + (((((kk<<5)+(lk<<3))<<1)) ^ ((lr&7)<<4));
  return *(const f16x8*)((const char*)wlds + byte);
}

// fuse -> intra-wave LDS transpose -> 32x 16B granule stores (lane<32)
__device__ __forceinline__ void store_tile(u16* tile, u16* dst_rowbase, int ubase,
                                           const float* hown, int lk, int l15, int lane){
#pragma unroll
  for (int j=0;j<4;j++) tile[(lk*4+j)*16 + l15] = f2h(hown[j]);
  LGK0; SB0;
  if (lane < 32){
    int r = lane >> 1, hf = lane & 1;
    f16x8 v = *(const f16x8*)(tile + r*16 + hf*8);   // 16B-aligned
    llc_st128(dst_rowbase + (size_t)r*H + ubase + hf*8, __builtin_bit_cast(u32x4, v));
  }
}

// ---------------- k0: prep ----------------
__global__ __launch_bounds__(256) void k0_prep(const float* __restrict__ wih,
                                               const float* __restrict__ h0in,
                                               u16* __restrict__ wih0f16,
                                               u16* __restrict__ h0i,
                                               u16* __restrict__ h1i,
                                               u32* __restrict__ cans){
  int i = blockIdx.x*256 + threadIdx.x;                  // 65536 threads
  for (int idx=i; idx<G3*H; idx+=65536) wih0f16[idx] = f2h(wih[idx]);
  if (i < 2*T*16) cans[i] = 0;                           // canA | canB
  if (i < B*H){ h0i[i] = f2h(h0in[i]); h1i[i] = f2h(h0in[B*H + i]); }
}

// ---------------- k1: gx0 GEMM  (out [t][gate][u][b] f16) ----------------
__global__ __launch_bounds__(256) void k1_gx(const float* __restrict__ x,
                                             const u16* __restrict__ wih0,
                                             const float* __restrict__ bih0,
                                             u16* __restrict__ gxT){
  int t  = blockIdx.x / 6, nb = blockIdx.x % 6;
  int wave = threadIdx.x >> 6, lane = threadIdx.x & 63;
  int l15 = lane & 15, lk = lane >> 4;
  int colbase = nb*256 + wave*64;
  f32x4 acc[2][4] = {};
#pragma unroll 4
  for (int kk=0; kk<16; kk++){
    int k0 = kk*32 + lk*8;
    f16x8 a[2];
#pragma unroll
    for (int bm=0; bm<2; bm++){
      const f32x4* xp_ = (const f32x4*)(x + ((size_t)(bm*16+l15)*T + t)*H + k0);
      f32x4 x0 = xp_[0], x1 = xp_[1];
      f16x8 v;
#pragma unroll
      for (int q=0;q<4;q++){ v[q]=(_Float16)x0[q]; v[4+q]=(_Float16)x1[q]; }
      a[bm] = v;
    }
#pragma unroll
    for (int nt=0; nt<4; nt++){
      int col = colbase + nt*16 + l15;
      f16x8 bf = *(const f16x8*)(wih0 + (size_t)col*H + k0);
      acc[0][nt] = MFMA16(a[0], bf, acc[0][nt]);
      acc[1][nt] = MFMA16(a[1], bf, acc[1][nt]);
    }
  }
#pragma unroll
  for (int nt=0; nt<4; nt++){
    int col = colbase + nt*16 + l15;
    float bias = bih0[col];
#pragma unroll
    for (int bm=0; bm<2; bm++){
      u32 lo = (u32)f2h(acc[bm][nt][0]+bias) | ((u32)f2h(acc[bm][nt][1]+bias) << 16);
      u32 hi = (u32)f2h(acc[bm][nt][2]+bias) | ((u32)f2h(acc[bm][nt][3]+bias) << 16);
      u32x2 v; v[0]=lo; v[1]=hi;
      *(u32x2*)(gxT + ((size_t)t*G3 + col)*B + bm*16 + lk*4) = v;
    }
  }
}

// ---------------- k2: persistent recurrence (32 WGs) ----------------
__global__ __launch_bounds__(256,1) void k2_recur(const float* __restrict__ h0in,
    const float* __restrict__ Wih, const float* __restrict__ bih,
    const float* __restrict__ Whh, const float* __restrict__ bhh,
    const u16* __restrict__ gxT,
    u16* __restrict__ h0all, u16* __restrict__ h1all,
    u32* __restrict__ canA, u32* __restrict__ canB,
    const u16* __restrict__ h0i, const u16* __restrict__ h1i,
    float* __restrict__ h1fin)
{
  __shared__ __align__(16) u16 wlds[96*512];
  __shared__ __align__(16) u16 wtile[4*256];
  const int wg = blockIdx.x, tid = threadIdx.x;
  const int wave = tid >> 6, lane = tid & 63;
  const int l15 = lane & 15, lk = lane >> 4;
  const int bm = wave >> 1, ug = wave & 1;
  u16* tile = wtile + wave*256;

  if (wg < 16){
    // ================= A: layer-0 spine =================
    const int slot  = wg;
    const int cu    = slot*32 + ug*16 + l15;
    const int ubase = slot*32 + ug*16;
    f16x8 wf[3][16]; load_wf(wf, Whh, cu, lk);
    const float bhr = bhh[cu], bhu = bhh[512+cu], bhn = bhh[1024+cu];
    float hown[4];
#pragma unroll
    for (int j=0;j<4;j++) hown[j] = h0in[(size_t)(bm*16+lk*4+j)*H + cu];

    // gx(0) prologue (plain loads; drained by first VMC0)
    u32x2 g0, g1, g2;
    { const u16* gp = gxT + ((size_t)0*G3 + cu)*B + bm*16 + lk*4;
      g0 = *(const u32x2*)gp; g1 = *(const u32x2*)(gp + (size_t)512*B);
      g2 = *(const u32x2*)(gp + (size_t)1024*B); }

    for (int t=0; t<T; t++){
      if (t > 0){
        const u32* p = canA + (size_t)(t-1)*16 + l15;    // one 64B line
        while (!__all(llc_poll(p) >= (u32)t)) {}
        SB0;
      }
      f16x8 af[16];
      if (t == 0){
        const u16* hr = h0i + (size_t)(bm*16+l15)*H + lk*8;
#pragma unroll
        for (int kk=0; kk<16; kk++) af[kk] = pl_ld16(hr + kk*32);
      } else {
        const u16* hr = h0all + ((size_t)(t-1)*B + bm*16 + l15)*H + lk*8;
#pragma unroll
        for (int kk=0; kk<16; kk++) af[kk] = llc_ld16(hr + kk*32);
      }
      // prefetch gx(t+1) under the h-read RT
      u32x2 ng0, ng1, ng2;
      { int tn = (t+1 < T) ? (t+1) : t;
        const u16* gp = gxT + ((size_t)tn*G3 + cu)*B + bm*16 + lk*4;
        ng0 = *(const u32x2*)gp; ng1 = *(const u32x2*)(gp + (size_t)512*B);
        ng2 = *(const u32x2*)(gp + (size_t)1024*B); }
      VMC0; SB0;
      f32x4 aR{}, aU{}, aN{};
#pragma unroll
      for (int kk=0; kk<16; kk++){
        aR = MFMA16(af[kk], wf[0][kk], aR);
        aU = MFMA16(af[kk], wf[1][kk], aU);
        aN = MFMA16(af[kk], wf[2][kk], aN);
      }
#pragma unroll
      for (int j=0;j<4;j++){
        float r = fsig(gxval(g0,j) + aR[j] + bhr);
        float u = fsig(gxval(g1,j) + aU[j] + bhu);
        float n = ftanh(gxval(g2,j) + r*(aN[j] + bhn));
        hown[j] = u*hown[j] + (1.f-u)*n;
      }
      store_tile(tile, h0all + ((size_t)t*B + bm*16)*H, ubase, hown, lk, l15, lane);
      VMC0;
      __syncthreads();                                   // all 4 waves drained
      if (tid == 0) llc_st32(canA + (size_t)t*16 + wg, (u32)(t+1));
      g0 = ng0; g1 = ng1; g2 = ng2;
    }
  } else {
    // ================= B: layer-1 (h-side regs + x-side LDS) =================
    const int slot = wg - 16;
    for (int idx = tid; idx < 96*64; idx += 256){
      int lr = idx >> 6, k8 = idx & 63;
      int g = lr >> 5, uu = lr & 31;
      const float* src = Wih + (size_t)G3*H + ((size_t)(g*512 + slot*32 + uu))*H + k8*8;
      f32x4 s0=*(const f32x4*)src, s1=*(const f32x4*)(src+4);
      f16x8 v;
#pragma unroll
      for (int e=0;e<4;e++){ v[e]=(_Float16)s0[e]; v[4+e]=(_Float16)s1[e]; }
      *(f16x8*)((char*)wlds + lr*1024 + ((k8*16) ^ ((lr&7)<<4))) = v;
    }
    __syncthreads();

    const int cu    = slot*32 + ug*16 + l15;
    const int ubase = slot*32 + ug*16;
    f16x8 wfh[3][16]; load_wf(wfh, Whh + (size_t)G3*H, cu, lk);
    const float br  = bih[G3 + cu]       + bhh[G3 + cu];
    const float bu_ = bih[G3 + 512 + cu] + bhh[G3 + 512 + cu];
    const float bni = bih[G3 + 1024 + cu];
    const float bnh = bhh[G3 + 1024 + cu];
    float hown[4];
#pragma unroll
    for (int j=0;j<4;j++) hown[j] = h0in[(size_t)B*H + (size_t)(bm*16+lk*4+j)*H + cu];

    const size_t rowoff = (size_t)(bm*16 + l15)*H + lk*8;

    for (int t=0; t<T; t++){
      // ---- ONE dual poll: canA(t) ready AND canB(t-1) ready ----
      {
        const u32* pA = canA + (size_t)t*16 + l15;
        const u32* pB = canB + (size_t)(t>0 ? t-1 : 0)*16 + l15;
        u32 wantA = (u32)(t+1), wantB = (t>0) ? (u32)t : 0u;
        u32 a, b;
        do { llc_poll2(pA, pB, a, b); } while (!__all(a >= wantA && b >= wantB));
        SB0;
      }
      // ---- ONE combined read burst: h1(t-1) + h0(t) ----
      f16x8 ah[16], ax[16];
      const u16* xr = h0all + (size_t)t*(B*H) + rowoff;
      const u16* hr = (t==0) ? (h1i + rowoff)
                             : (h1all + (size_t)(t-1)*(B*H) + rowoff);
      if (t == 0){
#pragma unroll
        for (int kk=0; kk<16; kk++) ah[kk] = pl_ld16(hr + kk*32);
      } else {
#pragma unroll
        for (int kk=0; kk<16; kk++) ah[kk] = llc_ld16(hr + kk*32);
      }
#pragma unroll
      for (int kk=0; kk<16; kk++) ax[kk] = llc_ld16(xr + kk*32);
      VMC0; SB0;
      f32x4 hR{}, hU{}, hN{};
#pragma unroll
      for (int kk=0; kk<16; kk++){
        hR = MFMA16(ah[kk], wfh[0][kk], hR);
        hU = MFMA16(ah[kk], wfh[1][kk], hU);
        hN = MFMA16(ah[kk], wfh[2][kk], hN);
      }
      f32x4 xR{}, xU{}, xN{};
#pragma unroll
      for (int kk=0; kk<16; kk++){
        xR = MFMA16(ax[kk], lds_frag(wlds,      ug*16, l15, lk, kk), xR);
        xU = MFMA16(ax[kk], lds_frag(wlds, 32 + ug*16, l15, lk, kk), xU);
        xN = MFMA16(ax[kk], lds_frag(wlds, 64 + ug*16, l15, lk, kk), xN);
      }
#pragma unroll
      for (int j=0;j<4;j++){
        float r = fsig(xR[j] + hR[j] + br);
        float u = fsig(xU[j] + hU[j] + bu_);
        float n = ftanh(xN[j] + bni + r*(hN[j] + bnh));
        hown[j] = u*hown[j] + (1.f-u)*n;
        if (t == T-1) h1fin[(size_t)(bm*16+lk*4+j)*H + cu] = hown[j];
      }
      store_tile(tile, h1all + ((size_t)t*B + bm*16)*H, ubase, hown, lk, l15, lane);
      VMC0;
      __syncthreads();
      if (tid == 0) llc_st32(canB + (size_t)t*16 + slot, (u32)(t+1));
    }
  }
}

// ---------------- k3: FC ----------------
__global__ __launch_bounds__(256) void k3_fc(const float* __restrict__ h1fin,
                                             const float* __restrict__ fcW,
                                             const float* __restrict__ fcb,
                                             float* __restrict__ out){
  int g = blockIdx.x*256 + threadIdx.x;     // 16384
  int b = g >> 9, o = g & 511;
  const f32x4* w = (const f32x4*)(fcW + (size_t)o*H);
  const f32x4* h = (const f32x4*)(h1fin + (size_t)b*H);
  float acc = fcb[o];
#pragma unroll 4
  for (int k=0;k<128;k++){
    f32x4 wv = w[k], hv = h[k];
    acc += wv[0]*hv[0] + wv[1]*hv[1] + wv[2]*hv[2] + wv[3]*hv[3];
  }
  out[g] = acc;
}

extern "C" void kernel_launch(void* const* d_in, const int* in_sizes, int n_in,
                              void* d_out, int out_size, void* d_ws, size_t ws_size,
                              hipStream_t stream) {
  const float* x    = (const float*)d_in[0];
  const float* h0   = (const float*)d_in[1];
  const float* Wih  = (const float*)d_in[2];
  const float* bihv = (const float*)d_in[3];
  const float* Whh  = (const float*)d_in[4];
  const float* bhhv = (const float*)d_in[5];
  const float* fcW  = (const float*)d_in[6];
  const float* fcb  = (const float*)d_in[7];
  float* out = (float*)d_out;

  char* ws = (char*)d_ws;
  u16* gxT     = (u16*)(ws + OFF_GX);
  u16* h0all   = (u16*)(ws + OFF_H0);
  u16* h1all   = (u16*)(ws + OFF_H1);
  u32* canA    = (u32*)(ws + OFF_CA);
  u32* canB    = (u32*)(ws + OFF_CB);
  u16* wih0f16 = (u16*)(ws + OFF_W0);
  u16* h0i     = (u16*)(ws + OFF_H0I);
  u16* h1i     = (u16*)(ws + OFF_H1I);
  float* h1fin = (float*)(ws + OFF_H1F);

  k0_prep<<<256, 256, 0, stream>>>(Wih, h0, wih0f16, h0i, h1i, canA);
  k1_gx<<<T*6, 256, 0, stream>>>(x, wih0f16, bihv, gxT);
  k2_recur<<<32, 256, 0, stream>>>(h0, Wih, bihv, Whh, bhhv, gxT,
                                   h0all, h1all, canA, canB, h0i, h1i, h1fin);
  k3_fc<<<64, 256, 0, stream>>>(h1fin, fcW, fcb, out);
}

// Round 11
// 7967.028 us; speedup vs baseline: 1.2227x; 1.0019x over previous
//
#include <hip/hip_runtime.h>
#include <hip/hip_bf16.h>

// GRU: L=2, B=32, T=1024, H=512, OUT=512
// Round 11: R2 (best measured, 6.02ms) + two isolated changes:
//   1. B wave-split: waves 2,3 = x-side (off-spine), waves 0,1 = h-side spine.
//      LDS partial exchange (double-buffered) + 1 barrier/step per side.
//   2. A's W_hh0 in registers (no LDS on A's chain).
// Everything else is R2 verbatim: 48 WGs (A=16, B=32), per-wave drained
// canaries, poll64(==), VMWAIT8/0 split, scattered 2B coherent stores.

typedef _Float16 f16x8 __attribute__((ext_vector_type(8)));
typedef float f32x4 __attribute__((ext_vector_type(4)));
typedef unsigned short u16;
typedef unsigned int u32;
typedef u32 u32x2 __attribute__((ext_vector_type(2)));

#define MFMA16(a,b,c) __builtin_amdgcn_mfma_f32_16x16x32_f16((a),(b),(c),0,0,0)
#define SB0 __builtin_amdgcn_sched_barrier(0)
#define VMWAIT8 asm volatile("s_waitcnt vmcnt(8)" ::: "memory")
#define VMWAIT0 asm volatile("s_waitcnt vmcnt(0)" ::: "memory")

static constexpr int B = 32, T = 1024, H = 512, G3 = 1536;

// ws layout (bytes)
static constexpr size_t OFF_GX  = 0;                               // 96MB f16 [t][gate][u][b]
static constexpr size_t OFF_H0  = OFF_GX + (size_t)T*G3*B*2;       // 32MB f16 [t][b][u]
static constexpr size_t OFF_H1  = OFF_H0 + (size_t)T*B*H*2;        // 32MB f16 [t][b][u]
static constexpr size_t OFF_CA  = OFF_H1 + (size_t)T*B*H*2;        // 256KB u32 [T][64]
static constexpr size_t OFF_CB  = OFF_CA + (size_t)T*64*4;         // 256KB u32 [T][64]
static constexpr size_t OFF_W0  = OFF_CB + (size_t)T*64*4;         // 1.5MB f16
static constexpr size_t OFF_H0I = OFF_W0 + (size_t)G3*H*2;         // 32KB f16
static constexpr size_t OFF_H1I = OFF_H0I + (size_t)B*H*2;         // 32KB f16
static constexpr size_t OFF_H1F = OFF_H1I + (size_t)B*H*2;         // 64KB f32

__device__ __forceinline__ u16 f2h(float x){ _Float16 h=(_Float16)x; return __builtin_bit_cast(u16,h); }
__device__ __forceinline__ float h2f(u16 u){ _Float16 h=__builtin_bit_cast(_Float16,u); return (float)h; }

// ---- device-scope (LLC) primitives — R2-proven ----
__device__ __forceinline__ u32 coh_load_u32(const u32* p){
  u32 r;
  asm volatile("global_load_dword %0, %1, off sc0 sc1\n\ts_waitcnt vmcnt(0)"
               : "=v"(r) : "v"(p) : "memory");
  return r;
}
__device__ __forceinline__ f16x8 coh_load16(const u16* p){   // NO waitcnt inside
  f16x8 r;
  asm volatile("global_load_dwordx4 %0, %1, off sc0 sc1" : "=v"(r) : "v"(p));
  return r;
}
__device__ __forceinline__ void coh_store_u16(u16* p, u32 v){
  asm volatile("global_store_short %0, %1, off sc0 sc1" :: "v"(p), "v"(v) : "memory");
}
__device__ __forceinline__ void coh_store_u32(u32* p, u32 v){
  asm volatile("global_store_dword %0, %1, off sc0 sc1" :: "v"(p), "v"(v) : "memory");
}

// poll 64 per-wave canaries in one coalesced 256B coherent read (R2)
__device__ __forceinline__ void poll64(const u32* base, u32 want, int lane){
  const u32* p = base + lane;
  while (!__all(coh_load_u32(p) == want)) {}
}

__device__ __forceinline__ float fsig(float x){ return 1.f/(1.f+__expf(-x)); }
__device__ __forceinline__ float ftanh(float x){
  x = fminf(15.f, fmaxf(-15.f, x));
  float e = __expf(-2.f*x);
  return (1.f-e)/(1.f+e);
}
__device__ __forceinline__ float gxval(u32x2 g, int j){
  u32 w = (j & 2) ? g[1] : g[0];
  return h2f((u16)(w >> ((j & 1) * 16)));
}

// W fragments (f32 -> f16) into registers; rows gate*512+cu, cols kk*32+lk*8
__device__ __forceinline__ void load_wf(f16x8 (*wf)[16], const float* Wbase, int cu, int lk){
#pragma unroll
  for (int g=0; g<3; g++)
#pragma unroll
    for (int kk=0; kk<16; kk++){
      const float* s = Wbase + ((size_t)(g*512 + cu))*H + kk*32 + lk*8;
      f32x4 s0 = *(const f32x4*)s, s1 = *(const f32x4*)(s+4);
      f16x8 v;
#pragma unroll
      for (int e=0; e<4; e++){ v[e]=(_Float16)s0[e]; v[4+e]=(_Float16)s1[e]; }
      wf[g][kk] = v;
    }
}
// MFMA B-operand fragment from XOR-swizzled LDS weights [96 rows][512] f16 (R2)
__device__ __forceinline__ f16x8 lds_frag(const u16* wlds, int lrbase, int l15, int lk, int kk){
  int lr = lrbase + l15;
  int byte = lr*1024 + (((((kk<<5)+(lk<<3))<<1)) ^ ((lr&7)<<4));
  return *(const f16x8*)((const char*)wlds + byte);
}

// ---------------- k0: prep ----------------
__global__ __launch_bounds__(256) void k0_prep(const float* __restrict__ wih,
                                               const float* __restrict__ h0in,
                                               u16* __restrict__ wih0f16,
                                               u16* __restrict__ h0i,
                                               u16* __restrict__ h1i,
                                               u32* __restrict__ cans){
  int i = blockIdx.x*256 + threadIdx.x;                  // 65536 threads
  for (int idx=i; idx<G3*H; idx+=65536) wih0f16[idx] = f2h(wih[idx]);
  cans[i] = 0; cans[i + 65536] = 0;                      // canA + canB
  if (i < B*H){ h0i[i] = f2h(h0in[i]); h1i[i] = f2h(h0in[B*H + i]); }
}

// ---------------- k1: gx0 GEMM  (out [t][gate][u][b] f16) ----------------
__global__ __launch_bounds__(256) void k1_gx(const float* __restrict__ x,
                                             const u16* __restrict__ wih0,
                                             const float* __restrict__ bih0,
                                             u16* __restrict__ gxT){
  int t  = blockIdx.x / 6, nb = blockIdx.x % 6;
  int wave = threadIdx.x >> 6, lane = threadIdx.x & 63;
  int l15 = lane & 15, lk = lane >> 4;
  int colbase = nb*256 + wave*64;
  f32x4 acc[2][4] = {};
#pragma unroll 4
  for (int kk=0; kk<16; kk++){
    int k0 = kk*32 + lk*8;
    f16x8 a[2];
#pragma unroll
    for (int bm=0; bm<2; bm++){
      const f32x4* xp_ = (const f32x4*)(x + ((size_t)(bm*16+l15)*T + t)*H + k0);
      f32x4 x0 = xp_[0], x1 = xp_[1];
      f16x8 v;
#pragma unroll
      for (int q=0;q<4;q++){ v[q]=(_Float16)x0[q]; v[4+q]=(_Float16)x1[q]; }
      a[bm] = v;
    }
#pragma unroll
    for (int nt=0; nt<4; nt++){
      int col = colbase + nt*16 + l15;
      f16x8 bf = *(const f16x8*)(wih0 + (size_t)col*H + k0);
      acc[0][nt] = MFMA16(a[0], bf, acc[0][nt]);
      acc[1][nt] = MFMA16(a[1], bf, acc[1][nt]);
    }
  }
#pragma unroll
  for (int nt=0; nt<4; nt++){
    int col = colbase + nt*16 + l15;
    float bias = bih0[col];
#pragma unroll
    for (int bm=0; bm<2; bm++){
      u32 lo = (u32)f2h(acc[bm][nt][0]+bias) | ((u32)f2h(acc[bm][nt][1]+bias) << 16);
      u32 hi = (u32)f2h(acc[bm][nt][2]+bias) | ((u32)f2h(acc[bm][nt][3]+bias) << 16);
      u32x2 v; v[0]=lo; v[1]=hi;
      *(u32x2*)(gxT + ((size_t)t*G3 + col)*B + bm*16 + lk*4) = v;
    }
  }
}

// ---------------- k2: persistent recurrence (48 WGs: A=16, B=32) ----------------
__global__ __launch_bounds__(256,1) void k2_recur(const float* __restrict__ h0in,
    const float* __restrict__ Wih, const float* __restrict__ bih,
    const float* __restrict__ Whh, const float* __restrict__ bhh,
    const u16* __restrict__ gxT,
    u16* __restrict__ h0all, u16* __restrict__ h1all,
    u32* __restrict__ canA, u32* __restrict__ canB,
    const u16* __restrict__ h0i, const u16* __restrict__ h1i,
    float* __restrict__ h1fin)
{
  __shared__ __align__(16) u16 wlds[96*512];
  __shared__ __align__(16) float part[2][2][64][12];   // [buf][bm][lane][xR xU xN]
  const int wg = blockIdx.x, tid = threadIdx.x;
  const int wave = tid >> 6, lane = tid & 63;
  const int l15 = lane & 15, lk = lane >> 4;

  if (wg < 16){
    // ================= A: layer-0 spine (4 waves, W in registers) =================
    const int bm = wave >> 1, ug = wave & 1;
    const int cu = wg*32 + ug*16 + l15;
    const int waveid = wg*4 + wave;
    f16x8 wf[3][16]; load_wf(wf, Whh, cu, lk);
    const float bhr = bhh[cu], bhu = bhh[512+cu], bhn = bhh[1024+cu];
    float hown[4];
#pragma unroll
    for (int j=0;j<4;j++) hown[j] = h0in[(size_t)(bm*16 + lk*4 + j)*H + cu];

    for (int t=0; t<T; t++){
      // gx(t) loads (plain; drained by the poll's vmcnt(0) or explicit wait)
      const u16* gp = gxT + ((size_t)t*G3 + cu)*B + bm*16 + lk*4;
      u32x2 g0 = *(const u32x2*)gp;
      u32x2 g1 = *(const u32x2*)(gp + (size_t)512*B);
      u32x2 g2 = *(const u32x2*)(gp + (size_t)1024*B);

      if (t > 0) poll64(canA + (size_t)(t-1)*64, (u32)t, lane);
      const u16* hrow = ((t==0) ? h0i : (h0all + (size_t)(t-1)*(B*H)))
                        + (size_t)(bm*16 + l15)*H + lk*8;
      f16x8 af[16];
#pragma unroll
      for (int kk=0; kk<16; kk++) af[kk] = coh_load16(hrow + kk*32);
      VMWAIT8; SB0;
      f32x4 aR{}, aU{}, aN{};
#pragma unroll
      for (int kk=0; kk<8; kk++){
        aR = MFMA16(af[kk], wf[0][kk], aR);
        aU = MFMA16(af[kk], wf[1][kk], aU);
        aN = MFMA16(af[kk], wf[2][kk], aN);
      }
      VMWAIT0; SB0;
#pragma unroll
      for (int kk=8; kk<16; kk++){
        aR = MFMA16(af[kk], wf[0][kk], aR);
        aU = MFMA16(af[kk], wf[1][kk], aU);
        aN = MFMA16(af[kk], wf[2][kk], aN);
      }
#pragma unroll
      for (int j=0;j<4;j++){
        float r = fsig(gxval(g0,j) + aR[j] + bhr);
        float u = fsig(gxval(g1,j) + aU[j] + bhu);
        float n = ftanh(gxval(g2,j) + r*(aN[j] + bhn));
        hown[j] = u*hown[j] + (1.f-u)*n;
        coh_store_u16(h0all + (size_t)t*(B*H) + (size_t)(bm*16 + lk*4 + j)*H + cu,
                      (u32)f2h(hown[j]));
      }
      VMWAIT0;
      if (lane == 0) coh_store_u32(canA + (size_t)t*64 + waveid, (u32)(t+1));
    }
  } else {
    // ================= B: layer-1 (32 WGs, wave-split) =================
    const int wg2 = wg - 16;                  // 0..31, owns 16 units
    const int u0  = wg2*16;
    // fill LDS: W_ih1 rows 0..47, W_hh1 rows 48..95 (R2 exact)
    for (int idx = tid; idx < 96*64; idx += 256){
      int lr = idx >> 6, k8 = idx & 63;
      const float* src;
      if (lr < 48){
        int gate = lr >> 4, ul = lr & 15;
        src = Wih + (size_t)G3*H + ((size_t)(gate*512 + u0 + ul))*H + k8*8;
      } else {
        int lr2 = lr - 48; int gate = lr2 >> 4, ul = lr2 & 15;
        src = Whh + (size_t)G3*H + ((size_t)(gate*512 + u0 + ul))*H + k8*8;
      }
      f16x8 v;
#pragma unroll
      for (int q=0;q<8;q++) v[q] = (_Float16)src[q];
      *(f16x8*)((char*)wlds + lr*1024 + ((k8*16) ^ ((lr&7)<<4))) = v;
    }
    __syncthreads();

    const int cu = u0 + l15;

    if (wave >= 2){
      // ---- x-side waves (off-spine): partial = h0(t) @ W_ih1^T ----
      const int bm = wave - 2;
      for (int t=0; t<T; t++){
        poll64(canA + (size_t)t*64, (u32)(t+1), lane);
        const u16* xrow = h0all + (size_t)t*(B*H) + (size_t)(bm*16 + l15)*H + lk*8;
        f16x8 ax[16];
#pragma unroll
        for (int kk=0; kk<16; kk++) ax[kk] = coh_load16(xrow + kk*32);
        VMWAIT8; SB0;
        f32x4 xR{}, xU{}, xN{};
#pragma unroll
        for (int kk=0; kk<8; kk++){
          xR = MFMA16(ax[kk], lds_frag(wlds,  0, l15, lk, kk), xR);
          xU = MFMA16(ax[kk], lds_frag(wlds, 16, l15, lk, kk), xU);
          xN = MFMA16(ax[kk], lds_frag(wlds, 32, l15, lk, kk), xN);
        }
        VMWAIT0; SB0;
#pragma unroll
        for (int kk=8; kk<16; kk++){
          xR = MFMA16(ax[kk], lds_frag(wlds,  0, l15, lk, kk), xR);
          xU = MFMA16(ax[kk], lds_frag(wlds, 16, l15, lk, kk), xU);
          xN = MFMA16(ax[kk], lds_frag(wlds, 32, l15, lk, kk), xN);
        }
        float* pp = &part[t&1][bm][lane][0];
        *(f32x4*)(pp+0) = xR; *(f32x4*)(pp+4) = xU; *(f32x4*)(pp+8) = xN;
        __syncthreads();
      }
    } else {
      // ---- h-side waves (the spine) ----
      const int bm = wave;
      const int waveid = wg2*2 + bm;          // 64 writers across 32 WGs
      const float br  = bih[G3 + cu]        + bhh[G3 + cu];
      const float bu_ = bih[G3 + 512 + cu]  + bhh[G3 + 512 + cu];
      const float bni = bih[G3 + 1024 + cu];
      const float bnh = bhh[G3 + 1024 + cu];
      float hown[4];
#pragma unroll
      for (int j=0;j<4;j++) hown[j] = h0in[(size_t)B*H + (size_t)(bm*16 + lk*4 + j)*H + cu];

      for (int t=0; t<T; t++){
        if (t > 0) poll64(canB + (size_t)(t-1)*64, (u32)t, lane);
        const u16* hrow = ((t==0) ? h1i : (h1all + (size_t)(t-1)*(B*H)))
                          + (size_t)(bm*16 + l15)*H + lk*8;
        f16x8 ah[16];
#pragma unroll
        for (int kk=0; kk<16; kk++) ah[kk] = coh_load16(hrow + kk*32);
        VMWAIT8; SB0;
        f32x4 hR{}, hU{}, hN{};
#pragma unroll
        for (int kk=0; kk<8; kk++){
          hR = MFMA16(ah[kk], lds_frag(wlds, 48, l15, lk, kk), hR);
          hU = MFMA16(ah[kk], lds_frag(wlds, 64, l15, lk, kk), hU);
          hN = MFMA16(ah[kk], lds_frag(wlds, 80, l15, lk, kk), hN);
        }
        VMWAIT0; SB0;
#pragma unroll
        for (int kk=8; kk<16; kk++){
          hR = MFMA16(ah[kk], lds_frag(wlds, 48, l15, lk, kk), hR);
          hU = MFMA16(ah[kk], lds_frag(wlds, 64, l15, lk, kk), hU);
          hN = MFMA16(ah[kk], lds_frag(wlds, 80, l15, lk, kk), hN);
        }
        __syncthreads();                       // x partials for t are ready
        const float* pp = &part[t&1][bm][lane][0];
        f32x4 xR = *(const f32x4*)(pp+0);
        f32x4 xU = *(const f32x4*)(pp+4);
        f32x4 xN = *(const f32x4*)(pp+8);
#pragma unroll
        for (int j=0;j<4;j++){
          float r = fsig(xR[j] + hR[j] + br);
          float u = fsig(xU[j] + hU[j] + bu_);
          float n = ftanh(xN[j] + bni + r*(hN[j] + bnh));
          hown[j] = u*hown[j] + (1.f-u)*n;
          int b = bm*16 + lk*4 + j;
          coh_store_u16(h1all + (size_t)t*(B*H) + (size_t)b*H + cu, (u32)f2h(hown[j]));
          if (t == T-1) h1fin[(size_t)b*H + cu] = hown[j];
        }
        VMWAIT0;
        if (lane == 0) coh_store_u32(canB + (size_t)t*64 + waveid, (u32)(t+1));
      }
    }
  }
}

// ---------------- k3: FC ----------------
__global__ __launch_bounds__(256) void k3_fc(const float* __restrict__ h1fin,
                                             const float* __restrict__ fcW,
                                             const float* __restrict__ fcb,
                                             float* __restrict__ out){
  int g = blockIdx.x*256 + threadIdx.x;     // 16384
  int b = g >> 9, o = g & 511;
  const f32x4* w = (const f32x4*)(fcW + (size_t)o*H);
  const f32x4* h = (const f32x4*)(h1fin + (size_t)b*H);
  float acc = fcb[o];
#pragma unroll 4
  for (int k=0;k<128;k++){
    f32x4 wv = w[k], hv = h[k];
    acc += wv[0]*hv[0] + wv[1]*hv[1] + wv[2]*hv[2] + wv[3]*hv[3];
  }
  out[g] = acc;
}

extern "C" void kernel_launch(void* const* d_in, const int* in_sizes, int n_in,
                              void* d_out, int out_size, void* d_ws, size_t ws_size,
                              hipStream_t stream) {
  const float* x    = (const float*)d_in[0];
  const float* h0   = (const float*)d_in[1];
  const float* Wih  = (const float*)d_in[2];
  const float* bihv = (const float*)d_in[3];
  const float* Whh  = (const float*)d_in[4];
  const float* bhhv = (const float*)d_in[5];
  const float* fcW  = (const float*)d_in[6];
  const float* fcb  = (const float*)d_in[7];
  float* out = (float*)d_out;

  char* ws = (char*)d_ws;
  u16* gxT     = (u16*)(ws + OFF_GX);
  u16* h0all   = (u16*)(ws + OFF_H0);
  u16* h1all   = (u16*)(ws + OFF_H1);
  u32* canA    = (u32*)(ws + OFF_CA);
  u32* canB    = (u32*)(ws + OFF_CB);
  u16* wih0f16 = (u16*)(ws + OFF_W0);
  u16* h0i     = (u16*)(ws + OFF_H0I);
  u16* h1i     = (u16*)(ws + OFF_H1I);
  float* h1fin = (float*)(ws + OFF_H1F);

  k0_prep<<<256, 256, 0, stream>>>(Wih, h0, wih0f16, h0i, h1i, canA);
  k1_gx<<<T*6, 256, 0, stream>>>(x, wih0f16, bihv, gxT);
  k2_recur<<<48, 256, 0, stream>>>(h0, Wih, bihv, Whh, bhhv, gxT,
                                   h0all, h1all, canA, canB, h0i, h1i, h1fin);
  k3_fc<<<64, 256, 0, stream>>>(h1fin, fcW, fcb, out);
}

// Round 12
// 5115.331 us; speedup vs baseline: 1.9044x; 1.5575x over previous
//
#include <hip/hip_runtime.h>
#include <hip/hip_bf16.h>

// GRU: L=2, B=32, T=1024, H=512, OUT=512
// Round 12: in-band LSB tags with CHEAP PROBE spin (fixes R7's retry-traffic
// pathology), drain-free tagged 16B granule producers (R9-proven mechanics).
//   A (WG 0..15): layer-0 spine, W_hh0 in regs. probe h0(t-1) -> burst ->
//                 48 MFMA -> fuse -> 32 tagged granules. No drain, no canary.
//   B (WG 16..47): layer-1, R2's exact 2-wave + LDS-weight structure.
//                 probe h1(t-1) -> combined burst {h1(t-1), h0(t)} -> validate
//                 both -> 96 MFMA -> fuse -> tagged granules.
// Probe: 64 lanes spread over (row=l15, u=32*l15+8*lk) -> covers every
// producer WG and every kk block; 16B/lane/iter (canary-poll cost).
// Correctness: granule valid iff all 8 u16 LSBs set (torn-store safe, R7).
// T-deep write-once buffers; k0 re-zeroes tags each call. Dep graph acyclic:
// A(t)<-A(t-1); B(t)<-{A(t), B(t-1)}. No rings, no claiming, no atomics.

typedef _Float16 f16x8 __attribute__((ext_vector_type(8)));
typedef float f32x4 __attribute__((ext_vector_type(4)));
typedef unsigned short u16;
typedef unsigned int u32;
typedef u32 u32x2 __attribute__((ext_vector_type(2)));
typedef u32 u32x4 __attribute__((ext_vector_type(4)));

#define MFMA16(a,b,c) __builtin_amdgcn_mfma_f32_16x16x32_f16((a),(b),(c),0,0,0)
#define SB0 __builtin_amdgcn_sched_barrier(0)
#define VMC0 asm volatile("s_waitcnt vmcnt(0)" ::: "memory")
#define LGK0 asm volatile("s_waitcnt lgkmcnt(0)" ::: "memory")

static constexpr int B = 32, T = 1024, H = 512, G3 = 1536;
static constexpr u32 M = 0x00010001u;

// ws layout (bytes)
static constexpr size_t OFF_GX  = 0;                               // 96MB f16 [t][gate][u][b]
static constexpr size_t OFF_H0  = OFF_GX + (size_t)T*G3*B*2;       // 32MB f16|LSB [t][b][u]
static constexpr size_t OFF_H1  = OFF_H0 + (size_t)T*B*H*2;        // 32MB f16|LSB [t][b][u]
static constexpr size_t OFF_W0  = OFF_H1 + (size_t)T*B*H*2;        // 1.5MB f16
static constexpr size_t OFF_H0I = OFF_W0 + (size_t)G3*H*2;         // 32KB f16
static constexpr size_t OFF_H1I = OFF_H0I + (size_t)B*H*2;         // 32KB f16
static constexpr size_t OFF_H1F = OFF_H1I + (size_t)B*H*2;         // 64KB f32
static constexpr size_t ZERO_BYTES = OFF_W0 - OFF_H0;              // 64MB tag region

__device__ __forceinline__ u16 f2h(float x){ _Float16 h=(_Float16)x; return __builtin_bit_cast(u16,h); }
__device__ __forceinline__ float h2f(u16 u){ _Float16 h=__builtin_bit_cast(_Float16,u); return (float)h; }

// ---- device-scope (LLC) primitives ----
__device__ __forceinline__ f16x8 llc_ld16(const u16* p){   // no wait
  f16x8 r; asm volatile("global_load_dwordx4 %0, %1, off sc0 sc1" : "=v"(r) : "v"(p)); return r;
}
__device__ __forceinline__ f16x8 pl_ld16(const u16* p){    // plain, no wait
  f16x8 r; asm volatile("global_load_dwordx4 %0, %1, off" : "=v"(r) : "v"(p)); return r;
}
__device__ __forceinline__ void llc_st128(u16* p, u32x4 v){
  asm volatile("global_store_dwordx4 %0, %1, off sc0 sc1" :: "v"(p), "v"(v) : "memory");
}

__device__ __forceinline__ float fsig(float x){ return 1.f/(1.f+__expf(-x)); }
__device__ __forceinline__ float ftanh(float x){
  x = fminf(15.f, fmaxf(-15.f, x));
  float e = __expf(-2.f*x);
  return (1.f-e)/(1.f+e);
}
__device__ __forceinline__ float gxval(u32x2 g, int j){
  u32 w = (j & 2) ? g[1] : g[0];
  return h2f((u16)(w >> ((j & 1) * 16)));
}
__device__ __forceinline__ u32 lsb_acc(f16x8 v){
  u32x4 w = __builtin_bit_cast(u32x4, v);
  return w[0] & w[1] & w[2] & w[3];
}

// cheap probe spin: lane probes granule (row base already per-lane), offset
// l15*32 u16 -> covers all producer slots and kk-blocks across the wave.
__device__ __forceinline__ void probe_spin(const u16* rowbase, int l15){
  const u16* p = rowbase + l15*32;
  for (;;){
    f16x8 v = llc_ld16(p); VMC0; SB0;
    if (__all((lsb_acc(v) & M) == M)) break;
  }
}

// W fragments (f32 -> f16) into registers
__device__ __forceinline__ void load_wf(f16x8 (*wf)[16], const float* Wbase, int cu, int lk){
#pragma unroll
  for (int g=0; g<3; g++)
#pragma unroll
    for (int kk=0; kk<16; kk++){
      const float* s = Wbase + ((size_t)(g*512 + cu))*H + kk*32 + lk*8;
      f32x4 s0 = *(const f32x4*)s, s1 = *(const f32x4*)(s+4);
      f16x8 v;
#pragma unroll
      for (int e=0; e<4; e++){ v[e]=(_Float16)s0[e]; v[4+e]=(_Float16)s1[e]; }
      wf[g][kk] = v;
    }
}
// MFMA B-operand fragment from XOR-swizzled LDS weights [96 rows][512] f16
__device__ __forceinline__ f16x8 lds_frag(const u16* wlds, int lrbase, int l15, int lk, int kk){
  int lr = lrbase + l15;
  int byte = lr*1024 + (((((kk<<5)+(lk<<3))<<1)) ^ ((lr&7)<<4));
  return *(const f16x8*)((const char*)wlds + byte);
}

// fuse -> intra-wave LDS transpose -> 32x tagged 16B granules, NO drain
__device__ __forceinline__ void store_tile(u16* tile, u16* dst_rowbase, int ubase,
                                           const float* hown, int lk, int l15, int lane){
#pragma unroll
  for (int j=0;j<4;j++) tile[(lk*4+j)*16 + l15] = f2h(hown[j]);
  LGK0; SB0;
  if (lane < 32){
    int r = lane >> 1, hf = lane & 1;
    f16x8 v = *(const f16x8*)(tile + r*16 + hf*8);
    u32x4 g = __builtin_bit_cast(u32x4, v);
    g[0] |= M; g[1] |= M; g[2] |= M; g[3] |= M;
    llc_st128(dst_rowbase + (size_t)r*H + ubase + hf*8, g);
  }
}

// ---------------- k0: prep ----------------
__global__ __launch_bounds__(256) void k0_prep(const float* __restrict__ wih,
                                               const float* __restrict__ h0in,
                                               u16* __restrict__ wih0f16,
                                               u16* __restrict__ h0i,
                                               u16* __restrict__ h1i,
                                               u32x4* __restrict__ zbase){
  int i = blockIdx.x*256 + threadIdx.x;                  // 65536 threads
  const int NZ = (int)(ZERO_BYTES / 16);
  u32x4 z; z[0]=0; z[1]=0; z[2]=0; z[3]=0;
  for (int idx=i; idx<NZ; idx+=65536) zbase[idx] = z;
  for (int idx=i; idx<G3*H; idx+=65536) wih0f16[idx] = f2h(wih[idx]);
  if (i < B*H){ h0i[i] = f2h(h0in[i]); h1i[i] = f2h(h0in[B*H + i]); }
}

// ---------------- k1: gx0 GEMM  (out [t][gate][u][b] f16) ----------------
__global__ __launch_bounds__(256) void k1_gx(const float* __restrict__ x,
                                             const u16* __restrict__ wih0,
                                             const float* __restrict__ bih0,
                                             u16* __restrict__ gxT){
  int t  = blockIdx.x / 6, nb = blockIdx.x % 6;
  int wave = threadIdx.x >> 6, lane = threadIdx.x & 63;
  int l15 = lane & 15, lk = lane >> 4;
  int colbase = nb*256 + wave*64;
  f32x4 acc[2][4] = {};
#pragma unroll 4
  for (int kk=0; kk<16; kk++){
    int k0 = kk*32 + lk*8;
    f16x8 a[2];
#pragma unroll
    for (int bm=0; bm<2; bm++){
      const f32x4* xp_ = (const f32x4*)(x + ((size_t)(bm*16+l15)*T + t)*H + k0);
      f32x4 x0 = xp_[0], x1 = xp_[1];
      f16x8 v;
#pragma unroll
      for (int q=0;q<4;q++){ v[q]=(_Float16)x0[q]; v[4+q]=(_Float16)x1[q]; }
      a[bm] = v;
    }
#pragma unroll
    for (int nt=0; nt<4; nt++){
      int col = colbase + nt*16 + l15;
      f16x8 bf = *(const f16x8*)(wih0 + (size_t)col*H + k0);
      acc[0][nt] = MFMA16(a[0], bf, acc[0][nt]);
      acc[1][nt] = MFMA16(a[1], bf, acc[1][nt]);
    }
  }
#pragma unroll
  for (int nt=0; nt<4; nt++){
    int col = colbase + nt*16 + l15;
    float bias = bih0[col];
#pragma unroll
    for (int bm=0; bm<2; bm++){
      u32 lo = (u32)f2h(acc[bm][nt][0]+bias) | ((u32)f2h(acc[bm][nt][1]+bias) << 16);
      u32 hi = (u32)f2h(acc[bm][nt][2]+bias) | ((u32)f2h(acc[bm][nt][3]+bias) << 16);
      u32x2 v; v[0]=lo; v[1]=hi;
      *(u32x2*)(gxT + ((size_t)t*G3 + col)*B + bm*16 + lk*4) = v;
    }
  }
}

// ---------------- k2: persistent recurrence (48 WGs: A=16, B=32) ----------------
__global__ __launch_bounds__(256,1) void k2_recur(const float* __restrict__ h0in,
    const float* __restrict__ Wih, const float* __restrict__ bih,
    const float* __restrict__ Whh, const float* __restrict__ bhh,
    const u16* __restrict__ gxT,
    u16* __restrict__ h0all, u16* __restrict__ h1all,
    const u16* __restrict__ h0i, const u16* __restrict__ h1i,
    float* __restrict__ h1fin)
{
  __shared__ __align__(16) u16 wlds[96*512];
  __shared__ __align__(16) u16 wtile[4*256];
  const int wg = blockIdx.x, tid = threadIdx.x;
  const int wave = tid >> 6, lane = tid & 63;
  const int l15 = lane & 15, lk = lane >> 4;
  u16* tile = wtile + wave*256;

  if (wg < 16){
    // ================= A: layer-0 spine (4 waves, W_hh0 in regs) =================
    const int bm = wave >> 1, ug = wave & 1;
    const int cu    = wg*32 + ug*16 + l15;
    const int ubase = wg*32 + ug*16;
    f16x8 wf[3][16]; load_wf(wf, Whh, cu, lk);
    const float bhr = bhh[cu], bhu = bhh[512+cu], bhn = bhh[1024+cu];
    float hown[4];
#pragma unroll
    for (int j=0;j<4;j++) hown[j] = h0in[(size_t)(bm*16 + lk*4 + j)*H + cu];

    for (int t=0; t<T; t++){
      // gx(t) plain loads — drained inside the probe/burst VMC0
      const u16* gp = gxT + ((size_t)t*G3 + cu)*B + bm*16 + lk*4;
      u32x2 g0 = *(const u32x2*)gp;
      u32x2 g1 = *(const u32x2*)(gp + (size_t)512*B);
      u32x2 g2 = *(const u32x2*)(gp + (size_t)1024*B);

      f16x8 af[16];
      if (t == 0){
        const u16* hr = h0i + (size_t)(bm*16+l15)*H + lk*8;
#pragma unroll
        for (int kk=0; kk<16; kk++) af[kk] = pl_ld16(hr + kk*32);
        VMC0; SB0;
      } else {
        const u16* hrow = h0all + ((size_t)(t-1)*B + bm*16 + l15)*H + lk*8;
        probe_spin(hrow, l15);
        for (;;){
#pragma unroll
          for (int kk=0; kk<16; kk++) af[kk] = llc_ld16(hrow + kk*32);
          VMC0; SB0;
          u32 acc = M;
#pragma unroll
          for (int kk=0; kk<16; kk++) acc &= lsb_acc(af[kk]);
          if (__all((acc & M) == M)) break;
        }
      }
      f32x4 aR{}, aU{}, aN{};
#pragma unroll
      for (int kk=0; kk<16; kk++){
        aR = MFMA16(af[kk], wf[0][kk], aR);
        aU = MFMA16(af[kk], wf[1][kk], aU);
        aN = MFMA16(af[kk], wf[2][kk], aN);
      }
#pragma unroll
      for (int j=0;j<4;j++){
        float r = fsig(gxval(g0,j) + aR[j] + bhr);
        float u = fsig(gxval(g1,j) + aU[j] + bhu);
        float n = ftanh(gxval(g2,j) + r*(aN[j] + bhn));
        hown[j] = u*hown[j] + (1.f-u)*n;
      }
      store_tile(tile, h0all + ((size_t)t*B + bm*16)*H, ubase, hown, lk, l15, lane);
      // no drain, no canary — consumer validates tags
    }
  } else {
    // ================= B: layer-1 (R2 structure: 2 active waves, W in LDS) =====
    const int wg2 = wg - 16;                   // 0..31, owns 16 units
    const int u0  = wg2*16;
    for (int idx = tid; idx < 96*64; idx += 256){
      int lr = idx >> 6, k8 = idx & 63;
      const float* src;
      if (lr < 48){
        int gate = lr >> 4, ul = lr & 15;
        src = Wih + (size_t)G3*H + ((size_t)(gate*512 + u0 + ul))*H + k8*8;
      } else {
        int lr2 = lr - 48; int gate = lr2 >> 4, ul = lr2 & 15;
        src = Whh + (size_t)G3*H + ((size_t)(gate*512 + u0 + ul))*H + k8*8;
      }
      f16x8 v;
#pragma unroll
      for (int q=0;q<8;q++) v[q] = (_Float16)src[q];
      *(f16x8*)((char*)wlds + lr*1024 + ((k8*16) ^ ((lr&7)<<4))) = v;
    }
    __syncthreads();
    if (wave >= 2) return;

    const int bm = wave;
    const int cu    = u0 + l15;
    const int ubase = u0;
    const float br  = bih[G3 + cu]        + bhh[G3 + cu];
    const float bu_ = bih[G3 + 512 + cu]  + bhh[G3 + 512 + cu];
    const float bni = bih[G3 + 1024 + cu];
    const float bnh = bhh[G3 + 1024 + cu];
    float hown[4];
#pragma unroll
    for (int j=0;j<4;j++) hown[j] = h0in[(size_t)B*H + (size_t)(bm*16 + lk*4 + j)*H + cu];

    const size_t rowoff = (size_t)(bm*16 + l15)*H + lk*8;

    for (int t=0; t<T; t++){
      f16x8 ah[16], ax[16];
      const u16* xrow = h0all + (size_t)t*(B*H) + rowoff;
      const u16* hrow = (t==0) ? (h1i + rowoff)
                               : (h1all + (size_t)(t-1)*(B*H) + rowoff);
      if (t > 0) probe_spin(hrow, l15);        // h1 spine probe (the binding dep)
      for (;;){
        if (t == 0){
#pragma unroll
          for (int kk=0; kk<16; kk++) ah[kk] = pl_ld16(hrow + kk*32);
        } else {
#pragma unroll
          for (int kk=0; kk<16; kk++) ah[kk] = llc_ld16(hrow + kk*32);
        }
#pragma unroll
        for (int kk=0; kk<16; kk++) ax[kk] = llc_ld16(xrow + kk*32);
        VMC0; SB0;
        u32 acc = M;
#pragma unroll
        for (int kk=0; kk<16; kk++) acc &= lsb_acc(ax[kk]);
        if (t > 0){
#pragma unroll
          for (int kk=0; kk<16; kk++) acc &= lsb_acc(ah[kk]);
        }
        if (__all((acc & M) == M)) break;
      }
      SB0;
      f32x4 hR{}, hU{}, hN{};
#pragma unroll
      for (int kk=0; kk<16; kk++){
        hR = MFMA16(ah[kk], lds_frag(wlds, 48, l15, lk, kk), hR);
        hU = MFMA16(ah[kk], lds_frag(wlds, 64, l15, lk, kk), hU);
        hN = MFMA16(ah[kk], lds_frag(wlds, 80, l15, lk, kk), hN);
      }
      f32x4 xR{}, xU{}, xN{};
#pragma unroll
      for (int kk=0; kk<16; kk++){
        xR = MFMA16(ax[kk], lds_frag(wlds,  0, l15, lk, kk), xR);
        xU = MFMA16(ax[kk], lds_frag(wlds, 16, l15, lk, kk), xU);
        xN = MFMA16(ax[kk], lds_frag(wlds, 32, l15, lk, kk), xN);
      }
#pragma unroll
      for (int j=0;j<4;j++){
        float r = fsig(xR[j] + hR[j] + br);
        float u = fsig(xU[j] + hU[j] + bu_);
        float n = ftanh(xN[j] + bni + r*(hN[j] + bnh));
        hown[j] = u*hown[j] + (1.f-u)*n;
        if (t == T-1) h1fin[(size_t)(bm*16+lk*4+j)*H + cu] = hown[j];
      }
      store_tile(tile, h1all + ((size_t)t*B + bm*16)*H, ubase, hown, lk, l15, lane);
    }
  }
}

// ---------------- k3: FC ----------------
__global__ __launch_bounds__(256) void k3_fc(const float* __restrict__ h1fin,
                                             const float* __restrict__ fcW,
                                             const float* __restrict__ fcb,
                                             float* __restrict__ out){
  int g = blockIdx.x*256 + threadIdx.x;     // 16384
  int b = g >> 9, o = g & 511;
  const f32x4* w = (const f32x4*)(fcW + (size_t)o*H);
  const f32x4* h = (const f32x4*)(h1fin + (size_t)b*H);
  float acc = fcb[o];
#pragma unroll 4
  for (int k=0;k<128;k++){
    f32x4 wv = w[k], hv = h[k];
    acc += wv[0]*hv[0] + wv[1]*hv[1] + wv[2]*hv[2] + wv[3]*hv[3];
  }
  out[g] = acc;
}

extern "C" void kernel_launch(void* const* d_in, const int* in_sizes, int n_in,
                              void* d_out, int out_size, void* d_ws, size_t ws_size,
                              hipStream_t stream) {
  const float* x    = (const float*)d_in[0];
  const float* h0   = (const float*)d_in[1];
  const float* Wih  = (const float*)d_in[2];
  const float* bihv = (const float*)d_in[3];
  const float* Whh  = (const float*)d_in[4];
  const float* bhhv = (const float*)d_in[5];
  const float* fcW  = (const float*)d_in[6];
  const float* fcb  = (const float*)d_in[7];
  float* out = (float*)d_out;

  char* ws = (char*)d_ws;
  u16* gxT     = (u16*)(ws + OFF_GX);
  u16* h0all   = (u16*)(ws + OFF_H0);
  u16* h1all   = (u16*)(ws + OFF_H1);
  u16* wih0f16 = (u16*)(ws + OFF_W0);
  u16* h0i     = (u16*)(ws + OFF_H0I);
  u16* h1i     = (u16*)(ws + OFF_H1I);
  float* h1fin = (float*)(ws + OFF_H1F);

  k0_prep<<<256, 256, 0, stream>>>(Wih, h0, wih0f16, h0i, h1i, (u32x4*)(ws + OFF_H0));
  k1_gx<<<T*6, 256, 0, stream>>>(x, wih0f16, bihv, gxT);
  k2_recur<<<48, 256, 0, stream>>>(h0, Wih, bihv, Whh, bhhv, gxT,
                                   h0all, h1all, h0i, h1i, h1fin);
  k3_fc<<<64, 256, 0, stream>>>(h1fin, fcW, fcb, out);
}